// Round 7
// baseline (156.115 us; speedup 1.0000x reference)
//
#include <hip/hip_runtime.h>

// ContextGenerator: B=32, D=NOTE_RES=64, T=4096, fp32.
// res[b,t] = sum_{L=low..min(63,up-1)} dm[b,L-1,t] * s_L[t]
// Group M (L=M+pad): s_L = P_M(pad) + sum_{k=pad}^{M-1} xC[k]*pm[k+pad].
//
// R6: staging-engine swap. R1/R3/R4/R5 all used global_load_lds DMA and all
// plateaued at ~2.5 TB/s aggregate staging (38-46 us) regardless of compute
// structure -> hypothesis: the LDS-DMA path itself caps ~2.5 TB/s. Now stage
// rep+pm via per-lane global_load_dwordx4 -> ds_write_b128 (the path m13
// proved at 6.29 TB/s). dm rows (used once each) skip LDS: per-wave register
// loads. LDS 34.3 KB -> 4 blocks/CU. Compute roles = R4 (verified), reading
// pm/rep from LDS per-FMA to keep VGPR low.

#define TT 4096

// Coarse-term k-range [K0, K0+8) of group32 (M=32). dmv[pad] = dm row 31+pad.
template <int K0>
__device__ __forceinline__ float roleK(const float* __restrict__ lrep,
                                       const float* __restrict__ lpm,
                                       const float* dmv, int lane, int low,
                                       int up) {
  constexpr int PADN = (K0 + 8 < 32) ? (K0 + 8) : 32;  // pads 0..PADN-1
  float xa[8];  // x1[K0..K0+7]
#pragma unroll
  for (int i = 0; i < 8; ++i)
    xa[i] = 0.5f * (lrep[(2 * (K0 + i)) * 64 + lane] +
                    lrep[(2 * (K0 + i) + 1) * 64 + lane]);
  float res = 0.f;
#pragma unroll
  for (int pad = 0; pad < PADN; ++pad) {
    const int L = 32 + pad;
    const int kk0 = (pad > K0) ? pad : K0;
    float s = 0.f;
#pragma unroll
    for (int k = kk0; k < K0 + 8; ++k)
      s = fmaf(xa[k - K0], lpm[(k + pad) * 64 + lane], s);
    if (L >= low && L < up) res = fmaf(dmv[pad], s, res);
  }
  return res;
}

// w3: group32 coarse k in [0,8) + whole M=16 level. dmv[0] = dm row 15.
__device__ __forceinline__ float role3(const float* __restrict__ lrep,
                                       const float* __restrict__ lpm,
                                       const float* dmv, int lane, int low,
                                       int up) {
  float x1[32];
#pragma unroll
  for (int j = 0; j < 32; ++j)
    x1[j] = 0.5f * (lrep[(2 * j) * 64 + lane] + lrep[(2 * j + 1) * 64 + lane]);
  float res = 0.f;
#pragma unroll
  for (int pad = 0; pad < 8; ++pad) {  // group32 k in [0,8)
    const int L = 32 + pad;
    float s = 0.f;
#pragma unroll
    for (int k = pad; k < 8; ++k) s = fmaf(x1[k], lpm[(k + pad) * 64 + lane], s);
    if (L >= low && L < up) res = fmaf(dmv[16 + pad], s, res);  // row 31+pad
  }
  float x2[16], q1[16];
#pragma unroll
  for (int j = 0; j < 16; ++j) {
    const float a = x1[2 * j], bb = x1[2 * j + 1];
    x2[j] = 0.5f * (a + bb);
    q1[j] = a * lpm[(2 * j) * 64 + lane] + bb * lpm[(2 * j + 1) * 64 + lane];
  }
  float p = 0.f;
#pragma unroll
  for (int pad = 0; pad < 16; ++pad) {  // M=16 level
    const int L = 16 + pad;
    float s = p;
#pragma unroll
    for (int k = pad; k < 16; ++k) s = fmaf(x2[k], lpm[(k + pad) * 64 + lane], s);
    if (L >= low && L < up) res = fmaf(dmv[pad], s, res);  // row 15+pad
    p += q1[pad];
  }
  return res;
}

// w4: group32 fine-prefix duty. dmv[0] = dm row 32.
__device__ __forceinline__ float role4(const float* __restrict__ lrep,
                                       const float* __restrict__ lpm,
                                       const float* dmv, int lane, int low,
                                       int up) {
  float res = 0.f, p = 0.f;
#pragma unroll
  for (int pad = 1; pad < 32; ++pad) {
    const int j = pad - 1;
    p = fmaf(lrep[(2 * j) * 64 + lane], lpm[(2 * j) * 64 + lane],
             fmaf(lrep[(2 * j + 1) * 64 + lane], lpm[(2 * j + 1) * 64 + lane],
                  p));
    const int L = 32 + pad;
    if (L >= low && L < up) res = fmaf(dmv[pad - 1], p, res);  // row 31+pad
  }
  return res;
}

// w5: M=8,4,2,1 levels. dmv[0] = dm row 0.
template <int M>
__device__ __forceinline__ void level_step(const float* __restrict__ lpm,
                                           const float* dmv, int lane, int low,
                                           int up, float* xf, float* xc,
                                           float& res) {
  float q[M];
#pragma unroll
  for (int j = 0; j < M; ++j) {
    const float a = xf[2 * j], bb = xf[2 * j + 1];
    xc[j] = 0.5f * (a + bb);
    q[j] = a * lpm[(2 * j) * 64 + lane] + bb * lpm[(2 * j + 1) * 64 + lane];
  }
  float p = 0.f;
#pragma unroll
  for (int pad = 0; pad < M; ++pad) {
    const int L = M + pad;
    float s = p;
#pragma unroll
    for (int k = pad; k < M; ++k) s = fmaf(xc[k], lpm[(k + pad) * 64 + lane], s);
    if (L >= low && L < up) res = fmaf(dmv[M - 1 + pad], s, res);
    p += q[pad];
  }
}

__device__ __forceinline__ float role5(const float* __restrict__ lrep,
                                       const float* __restrict__ lpm,
                                       const float* dmv, int lane, int low,
                                       int up) {
  float x1[32];
#pragma unroll
  for (int j = 0; j < 32; ++j)
    x1[j] = 0.5f * (lrep[(2 * j) * 64 + lane] + lrep[(2 * j + 1) * 64 + lane]);
  float x2[16];
#pragma unroll
  for (int j = 0; j < 16; ++j) x2[j] = 0.5f * (x1[2 * j] + x1[2 * j + 1]);
  float res = 0.f;
  float x3[8], x4[4], x5[2], x6[1];
  level_step<8>(lpm, dmv, lane, low, up, x2, x3, res);
  level_step<4>(lpm, dmv, lane, low, up, x3, x4, res);
  level_step<2>(lpm, dmv, lane, low, up, x4, x5, res);
  level_step<1>(lpm, dmv, lane, low, up, x5, x6, res);
  return res;
}

__global__ __launch_bounds__(384) void ContextGenerator_34875134444049_kernel(
    const float* __restrict__ rep, const float* __restrict__ dm,
    const float* __restrict__ pm, const int* __restrict__ lowp,
    const int* __restrict__ upp, float* __restrict__ out) {
  // 128 data rows (64 rep | 64 pm) * 256 B + 6*64 partials = 34304 B.
  __shared__ float lds[128 * 64 + 6 * 64];
  const int tid = threadIdx.x;
  const int wid = tid >> 6;
  const int lane = tid & 63;
  const int b = blockIdx.x >> 6;          // 2048 blocks: 64 chunks per batch
  const int t0 = (blockIdx.x & 63) << 6;  // 64-t slice
  const size_t base = (size_t)b * 64 * TT + (size_t)t0;

  // --- staging: per-lane dwordx4 loads (the 6.3 TB/s-proven path).
  // Thread covers float4 slot (tid>>4 + 24g, (tid&15)*4); 6 passes, rows<128.
  const int rcol = (tid & 15) << 2;
  float4 v[6];
#pragma unroll
  for (int g = 0; g < 6; ++g) {
    const int row = (tid >> 4) + 24 * g;
    if (row < 128) {
      const float* tb = (row < 64) ? rep + base + (size_t)row * TT
                                   : pm + base + (size_t)(row - 64) * TT;
      v[g] = *(const float4*)(tb + rcol);
    }
  }

  // --- dm per-wave register loads (independent; overlap staging latency).
  const int low = lowp[0];
  const int up = upp[0];
  const float* dmg = dm + base + lane;
  float dmv[32];
  if (wid == 0) {
#pragma unroll
    for (int i = 0; i < 32; ++i) dmv[i] = dmg[(size_t)(31 + i) * TT];
  } else if (wid == 1) {
#pragma unroll
    for (int i = 0; i < 24; ++i) dmv[i] = dmg[(size_t)(31 + i) * TT];
  } else if (wid == 2) {
#pragma unroll
    for (int i = 0; i < 16; ++i) dmv[i] = dmg[(size_t)(31 + i) * TT];
  } else if (wid == 3) {
#pragma unroll
    for (int i = 0; i < 24; ++i) dmv[i] = dmg[(size_t)(15 + i) * TT];
  } else if (wid == 4) {
#pragma unroll
    for (int i = 0; i < 31; ++i) dmv[i] = dmg[(size_t)(32 + i) * TT];
  } else {
#pragma unroll
    for (int i = 0; i < 15; ++i) dmv[i] = dmg[(size_t)i * TT];
  }

  // --- LDS writes (ds_write_b128), then one barrier.
#pragma unroll
  for (int g = 0; g < 6; ++g) {
    const int row = (tid >> 4) + 24 * g;
    if (row < 128) *(float4*)(&lds[row * 64 + rcol]) = v[g];
  }
  __syncthreads();

  const float* lrep = lds;
  const float* lpm = lds + 64 * 64;
  float* part = lds + 128 * 64;

  float res;
  if (wid == 0)
    res = roleK<24>(lrep, lpm, dmv, lane, low, up);
  else if (wid == 1)
    res = roleK<16>(lrep, lpm, dmv, lane, low, up);
  else if (wid == 2)
    res = roleK<8>(lrep, lpm, dmv, lane, low, up);
  else if (wid == 3)
    res = role3(lrep, lpm, dmv, lane, low, up);
  else if (wid == 4)
    res = role4(lrep, lpm, dmv, lane, low, up);
  else
    res = role5(lrep, lpm, dmv, lane, low, up);

  if (wid > 0) part[wid * 64 + lane] = res;
  __syncthreads();
  if (wid == 0)
    out[(size_t)b * TT + t0 + lane] = res + part[64 + lane] + part[128 + lane] +
                                      part[192 + lane] + part[256 + lane] +
                                      part[320 + lane];
}

extern "C" void kernel_launch(void* const* d_in, const int* in_sizes, int n_in,
                              void* d_out, int out_size, void* d_ws,
                              size_t ws_size, hipStream_t stream) {
  const float* rep = (const float*)d_in[0];
  const float* dm = (const float*)d_in[1];
  const float* pm = (const float*)d_in[2];
  const int* lowp = (const int*)d_in[3];
  const int* upp = (const int*)d_in[4];
  float* out = (float*)d_out;

  const int blocks = out_size / 64;  // 131072 / 64 = 2048
  ContextGenerator_34875134444049_kernel<<<blocks, 384, 0, stream>>>(
      rep, dm, pm, lowp, upp, out);
}

// Round 8
// 123.005 us; speedup vs baseline: 1.2692x; 1.2692x over previous
//
#include <hip/hip_runtime.h>

// ContextGenerator: B=32, D=NOTE_RES=64, T=4096, fp32.
// res[b,t] = sum_{L=low..min(63,up-1)} dm[b,L-1,t] * s_L[t]
// Group M (L=M+pad): s_L = P_M(pad) + sum_{k=pad}^{M-1} xC[k]*pm[k+pad].
//
// R7: clean staging-engine A/B vs R4. Structure is EXACTLY R4 (one-shot 2048
// blocks, 6 waves, 50688 B LDS holding rep|pm|dm, verified roles reading all
// operands from LDS -> no big per-thread arrays -> no spills). Only change:
// staging is 8x per-lane global_load_dwordx4 -> 8x ds_write_b128 (the m13
// 6.29 TB/s path) instead of 48x width-16 global_load_lds DMA (which pinned
// R1/R3/R4/R5 at ~2.5 TB/s aggregate regardless of compute structure).

#define TT 4096

// Coarse-term k-range [K0, K0+8) of group32 (M=32).
template <int K0>
__device__ __forceinline__ float roleK(const float* __restrict__ lrep,
                                       const float* __restrict__ lpm,
                                       const float* __restrict__ ldm, int lane,
                                       int low, int up) {
  constexpr int PADN = (K0 + 8 < 32) ? (K0 + 8) : 32;  // pads 0..PADN-1
  constexpr int PMN = (2 * K0 + 14 < 62 ? 2 * K0 + 14 : 62) - K0 + 1;
  float xa[8];  // x1[K0..K0+7]
#pragma unroll
  for (int i = 0; i < 8; ++i)
    xa[i] = 0.5f * (lrep[(2 * (K0 + i)) * 64 + lane] +
                    lrep[(2 * (K0 + i) + 1) * 64 + lane]);
  float pmv[PMN];
#pragma unroll
  for (int r = 0; r < PMN; ++r) pmv[r] = lpm[(K0 + r) * 64 + lane];
  float res = 0.f;
#pragma unroll
  for (int pad = 0; pad < PADN; ++pad) {
    const int L = 32 + pad;
    const int kk0 = (pad > K0) ? pad : K0;
    float s = 0.f;
#pragma unroll
    for (int k = kk0; k < K0 + 8; ++k)
      s = fmaf(xa[k - K0], pmv[k + pad - K0], s);
    if (L >= low && L < up) res = fmaf(ldm[(31 + pad) * 64 + lane], s, res);
  }
  return res;
}

// w3: group32 coarse k in [0,8)  +  the whole M=16 level.
__device__ __forceinline__ float role3(const float* __restrict__ lrep,
                                       const float* __restrict__ lpm,
                                       const float* __restrict__ ldm, int lane,
                                       int low, int up) {
  float pmv[31];  // pm rows 0..30
#pragma unroll
  for (int r = 0; r < 31; ++r) pmv[r] = lpm[r * 64 + lane];
  float x1[32];
#pragma unroll
  for (int j = 0; j < 32; ++j)
    x1[j] = 0.5f * (lrep[(2 * j) * 64 + lane] + lrep[(2 * j + 1) * 64 + lane]);
  float res = 0.f;
#pragma unroll
  for (int pad = 0; pad < 8; ++pad) {
    const int L = 32 + pad;
    float s = 0.f;
#pragma unroll
    for (int k = pad; k < 8; ++k) s = fmaf(x1[k], pmv[k + pad], s);
    if (L >= low && L < up) res = fmaf(ldm[(31 + pad) * 64 + lane], s, res);
  }
  float x2[16], q1[16];
#pragma unroll
  for (int j = 0; j < 16; ++j) {
    const float a = x1[2 * j], bb = x1[2 * j + 1];
    x2[j] = 0.5f * (a + bb);
    q1[j] = a * pmv[2 * j] + bb * pmv[2 * j + 1];
  }
  float p = 0.f;
#pragma unroll
  for (int pad = 0; pad < 16; ++pad) {
    const int L = 16 + pad;
    float s = p;
#pragma unroll
    for (int k = pad; k < 16; ++k) s = fmaf(x2[k], pmv[k + pad], s);
    if (L >= low && L < up) res = fmaf(ldm[(15 + pad) * 64 + lane], s, res);
    p += q1[pad];
  }
  return res;
}

// w4: group32 fine-prefix duty.
__device__ __forceinline__ float role4(const float* __restrict__ lrep,
                                       const float* __restrict__ lpm,
                                       const float* __restrict__ ldm, int lane,
                                       int low, int up) {
  float res = 0.f, p = 0.f;
#pragma unroll
  for (int pad = 1; pad < 32; ++pad) {
    const int j = pad - 1;
    p = fmaf(lrep[(2 * j) * 64 + lane], lpm[(2 * j) * 64 + lane],
             fmaf(lrep[(2 * j + 1) * 64 + lane], lpm[(2 * j + 1) * 64 + lane],
                  p));
    const int L = 32 + pad;
    if (L >= low && L < up) res = fmaf(ldm[(31 + pad) * 64 + lane], p, res);
  }
  return res;
}

// w5: M=8,4,2,1 levels.
template <int M>
__device__ __forceinline__ void level_step(const float* pmv,
                                           const float* __restrict__ ldm,
                                           int lane, int low, int up, float* xf,
                                           float* xc, float& res) {
  float q[M];
#pragma unroll
  for (int j = 0; j < M; ++j) {
    const float a = xf[2 * j], bb = xf[2 * j + 1];
    xc[j] = 0.5f * (a + bb);
    q[j] = a * pmv[2 * j] + bb * pmv[2 * j + 1];
  }
  float p = 0.f;
#pragma unroll
  for (int pad = 0; pad < M; ++pad) {
    const int L = M + pad;
    float s = p;
#pragma unroll
    for (int k = pad; k < M; ++k) s = fmaf(xc[k], pmv[k + pad], s);
    if (L >= low && L < up) res = fmaf(ldm[(M - 1 + pad) * 64 + lane], s, res);
    p += q[pad];
  }
}

__device__ __forceinline__ float role5(const float* __restrict__ lrep,
                                       const float* __restrict__ lpm,
                                       const float* __restrict__ ldm, int lane,
                                       int low, int up) {
  float pmv[15];  // pm rows 0..14
#pragma unroll
  for (int r = 0; r < 15; ++r) pmv[r] = lpm[r * 64 + lane];
  float x1[32];
#pragma unroll
  for (int j = 0; j < 32; ++j)
    x1[j] = 0.5f * (lrep[(2 * j) * 64 + lane] + lrep[(2 * j + 1) * 64 + lane]);
  float x2[16];
#pragma unroll
  for (int j = 0; j < 16; ++j) x2[j] = 0.5f * (x1[2 * j] + x1[2 * j + 1]);
  float res = 0.f;
  float x3[8], x4[4], x5[2], x6[1];
  level_step<8>(pmv, ldm, lane, low, up, x2, x3, res);
  level_step<4>(pmv, ldm, lane, low, up, x3, x4, res);
  level_step<2>(pmv, ldm, lane, low, up, x4, x5, res);
  level_step<1>(pmv, ldm, lane, low, up, x5, x6, res);
  return res;
}

__global__ __launch_bounds__(384, 3) void ContextGenerator_34875134444049_kernel(
    const float* __restrict__ rep, const float* __restrict__ dm,
    const float* __restrict__ pm, const int* __restrict__ lowp,
    const int* __restrict__ upp, float* __restrict__ out) {
  // 192 data rows (64 rep | 64 pm | 64 dm) * 256 B + 6*64 partials = 50688 B
  __shared__ float lds[192 * 64 + 6 * 64];
  const int tid = threadIdx.x;
  const int wid = tid >> 6;
  const int lane = tid & 63;
  const int b = blockIdx.x >> 6;          // 2048 blocks: 64 chunks per batch
  const int t0 = (blockIdx.x & 63) << 6;  // 64-t slice
  const size_t base = (size_t)b * 64 * TT + (size_t)t0;

  // --- staging: 8 independent per-lane dwordx4 loads (m13's 6.3 TB/s path),
  // then 8 ds_write_b128. Slot s (0..3071) = row s>>4, float4 col s&15.
  float4 v[8];
#pragma unroll
  for (int g = 0; g < 8; ++g) {
    const int slot = tid + 384 * g;
    const int row = slot >> 4;
    const int c4 = (slot & 15) << 2;
    const float* tb = (row < 64) ? rep + base + (size_t)row * TT
                    : (row < 128) ? pm + base + (size_t)(row - 64) * TT
                                  : dm + base + (size_t)(row - 128) * TT;
    v[g] = *(const float4*)(tb + c4);
  }
#pragma unroll
  for (int g = 0; g < 8; ++g) {
    const int slot = tid + 384 * g;
    *(float4*)(&lds[slot << 2]) = v[g];
  }

  const int low = lowp[0];
  const int up = upp[0];

  __syncthreads();

  const float* lrep = lds;
  const float* lpm = lds + 64 * 64;
  const float* ldm = lds + 128 * 64;
  float* part = lds + 192 * 64;

  float res;
  if (wid == 0)
    res = roleK<24>(lrep, lpm, ldm, lane, low, up);
  else if (wid == 1)
    res = roleK<16>(lrep, lpm, ldm, lane, low, up);
  else if (wid == 2)
    res = roleK<8>(lrep, lpm, ldm, lane, low, up);
  else if (wid == 3)
    res = role3(lrep, lpm, ldm, lane, low, up);
  else if (wid == 4)
    res = role4(lrep, lpm, ldm, lane, low, up);
  else
    res = role5(lrep, lpm, ldm, lane, low, up);

  if (wid > 0) part[wid * 64 + lane] = res;
  __syncthreads();
  if (wid == 0)
    out[(size_t)b * TT + t0 + lane] = res + part[64 + lane] + part[128 + lane] +
                                      part[192 + lane] + part[256 + lane] +
                                      part[320 + lane];
}

extern "C" void kernel_launch(void* const* d_in, const int* in_sizes, int n_in,
                              void* d_out, int out_size, void* d_ws,
                              size_t ws_size, hipStream_t stream) {
  const float* rep = (const float*)d_in[0];
  const float* dm = (const float*)d_in[1];
  const float* pm = (const float*)d_in[2];
  const int* lowp = (const int*)d_in[3];
  const int* upp = (const int*)d_in[4];
  float* out = (float*)d_out;

  const int blocks = out_size / 64;  // 131072 / 64 = 2048
  ContextGenerator_34875134444049_kernel<<<blocks, 384, 0, stream>>>(
      rep, dm, pm, lowp, upp, out);
}